// Round 7
// baseline (287.908 us; speedup 1.0000x reference)
//
#include <hip/hip_runtime.h>
#include <hip/hip_cooperative_groups.h>

namespace cg = cooperative_groups;

#define IMH 512
#define IMW 512
#define BATCH 8
#define NTOK 20480
#define NC 4096
#define NF 16384
#define ED 128

typedef float vf4 __attribute__((ext_vector_type(4)));

__device__ __forceinline__ void nt_store4(float* p, float a, float b, float c, float d) {
    vf4 v = {a, b, c, d};
    __builtin_nontemporal_store(v, (vf4*)p);
}
__device__ __forceinline__ void nt_store4v(float* p, float4 v) {
    nt_store4(p, v.x, v.y, v.z, v.w);
}

// ---- role: edge (blocks 0-511): one 64x64 tile -> 16x16 fp64 cells + tile sum
__device__ __forceinline__ void edge_role(int blk, int t,
                                          const float* __restrict__ x,
                                          double* __restrict__ edges,
                                          double* __restrict__ tsum) {
    __shared__ float esm[66][68];
    __shared__ double dred[4];
    int lane = t & 63, wid = t >> 6;
    int b = blk >> 6;
    int tile = blk & 63;
    int ty0 = (tile >> 3) * 64;
    int tx0 = (tile & 7) * 64;
    const float* img = x + (size_t)b * (IMH * IMW);
    for (int idx = t; idx < 66 * 66; idx += 256) {
        int r = idx / 66, c = idx - r * 66;
        int gy = ty0 - 1 + r, gx = tx0 - 1 + c;
        float v = 0.f;
        if (gy >= 0 && gy < IMH && gx >= 0 && gx < IMW) v = img[gy * IMW + gx];
        esm[r][c] = v;
    }
    __syncthreads();
    int cy = t >> 4, cx = t & 15;
    double acc = 0.0;
    #pragma unroll
    for (int dy = 0; dy < 4; ++dy) {
        int py = cy * 4 + dy + 1;
        #pragma unroll
        for (int dx = 0; dx < 4; ++dx) {
            int px = cx * 4 + dx + 1;
            double a00 = (double)esm[py - 1][px - 1];
            double a01 = (double)esm[py - 1][px];
            double a02 = (double)esm[py - 1][px + 1];
            double a10 = (double)esm[py][px - 1];
            double a12 = (double)esm[py][px + 1];
            double a20 = (double)esm[py + 1][px - 1];
            double a21 = (double)esm[py + 1][px];
            double a22 = (double)esm[py + 1][px + 1];
            double sx = (a02 + 2.0 * a12 + a22) - (a00 + 2.0 * a10 + a20);
            double sy = (a20 + 2.0 * a21 + a22) - (a00 + 2.0 * a01 + a02);
            acc += sqrt(sx * sx + sy * sy);
        }
    }
    double cell = acc * (1.0 / 16.0);
    int gy = (ty0 >> 2) + cy;
    int gx = (tx0 >> 2) + cx;
    edges[((size_t)b << 14) + gy * 128 + gx] = cell;
    double sc = cell;
    #pragma unroll
    for (int off = 32; off > 0; off >>= 1) sc += __shfl_xor(sc, off);
    if (lane == 0) dred[wid] = sc;
    __syncthreads();
    if (t == 0) tsum[b * 64 + tile] = dred[0] + dred[1] + dred[2] + dred[3];
}

// ---- role: coarse (all 1024 blocks): 32 patches, wave-uniform scalar loads
__device__ __forceinline__ void coarse_role(int blk, int t,
                                            const float* __restrict__ x,
                                            const float* __restrict__ wc,
                                            const float* __restrict__ bc,
                                            const float* __restrict__ temb,
                                            float* __restrict__ out) {
    int lane = t & 63;
    int b = blk >> 7;
    int pblk = (blk & 127) * 32;
    int wv = __builtin_amdgcn_readfirstlane(t >> 6);  // wave id 0..3
    int h = wv & 1;
    int p0 = pblk + (wv >> 1) * 16;
    int d = h * 64 + lane;
    float wcol[64];
    #pragma unroll
    for (int k = 0; k < 64; ++k) wcol[k] = wc[k * ED + d];
    float base = bc[d] + temb[d];
    const float* img = x + ((size_t)b * IMH + (p0 >> 6) * 8) * IMW + (p0 & 63) * 8;
    float* dst = out + ((size_t)b * NTOK + p0) * ED + d;
    #pragma unroll
    for (int p = 0; p < 16; ++p) {
        const float* pimg = img + p * 8;    // wave-uniform -> scalar loads
        float acc = base;
        #pragma unroll
        for (int r = 0; r < 8; ++r) {
            const float* rp = pimg + r * IMW;
            acc += rp[0] * wcol[r * 8 + 0] + rp[1] * wcol[r * 8 + 1]
                 + rp[2] * wcol[r * 8 + 2] + rp[3] * wcol[r * 8 + 3]
                 + rp[4] * wcol[r * 8 + 4] + rp[5] * wcol[r * 8 + 5]
                 + rp[6] * wcol[r * 8 + 6] + rp[7] * wcol[r * 8 + 7];
        }
        __builtin_nontemporal_store(acc, dst + (size_t)p * ED);
    }
}

// ---- role: scan (blocks 0-63): mean, mask, intra-block prefix positions
__device__ __forceinline__ void scan_role(int blk, int t,
                                          const double* __restrict__ edges,
                                          const double* __restrict__ tsum,
                                          int* __restrict__ pos_rel,
                                          int* __restrict__ btot,
                                          float* __restrict__ mask_out) {
    __shared__ int ired[4];
    int lane = t & 63, wid = t >> 6;
    int b = blk >> 3;
    int s = blk & 7;
    // deterministic fixed-order fp64 mean
    double total = 0.0;
    const double* ts = tsum + b * 64;
    #pragma unroll
    for (int j = 0; j < 64; ++j) total += ts[j];
    double mean = total * (1.0 / 16384.0);
    // exactly this thread's 8 cells
    const double* e = edges + ((size_t)b << 14) + s * 2048 + t * 8;
    double v[8];
    #pragma unroll
    for (int j = 0; j < 4; ++j) {
        double2 dv = *(const double2*)&e[j * 2];
        v[2 * j] = dv.x;
        v[2 * j + 1] = dv.y;
    }
    int m[8], cnt = 0;
    #pragma unroll
    for (int j = 0; j < 8; ++j) { m[j] = (v[j] > mean) ? 1 : 0; cnt += m[j]; }
    int incl = cnt;
    #pragma unroll
    for (int off = 1; off < 64; off <<= 1) {
        int up = __shfl_up(incl, off);
        if (lane >= off) incl += up;
    }
    if (lane == 63) ired[wid] = incl;
    __syncthreads();
    int woff = 0, btotal = 0;
    #pragma unroll
    for (int w = 0; w < 4; ++w) { int c = ired[w]; btotal += c; if (w < wid) woff += c; }
    int run = woff + incl - cnt;
    float mf[8]; int pv[8];
    #pragma unroll
    for (int j = 0; j < 8; ++j) {
        pv[j] = m[j] ? run : -1;
        run += m[j];
        mf[j] = m[j] ? 1.0f : 0.0f;
    }
    float* mb = mask_out + ((size_t)b << 14) + s * 2048 + t * 8;
    int* pb = pos_rel + ((size_t)b << 14) + s * 2048 + t * 8;
    nt_store4(&mb[0], mf[0], mf[1], mf[2], mf[3]);
    nt_store4(&mb[4], mf[4], mf[5], mf[6], mf[7]);
    *(int4*)&pb[0] = make_int4(pv[0], pv[1], pv[2], pv[3]);
    *(int4*)&pb[4] = make_int4(pv[4], pv[5], pv[6], pv[7]);
    if (t == 0) btot[b * 8 + s] = btotal;
}

// ---- role: fine (all 1024 blocks): one patch-row (128 patches), scatter+fill
__device__ __forceinline__ void fine_role(int blk, int t,
                                          const float* __restrict__ x,
                                          const float* __restrict__ wfp,
                                          const float* __restrict__ bfp,
                                          const float* __restrict__ temb,
                                          const int* __restrict__ pos_rel,
                                          const int* __restrict__ btot,
                                          float* __restrict__ out) {
    __shared__ float smx[4][512];
    int b = blk >> 7;
    int row = blk & 127;
    int i0 = row * 128;
    int sblk = i0 >> 11;                       // owning scan-block (0..7)
    int off = 0, K = 0;
    const int* bt = btot + b * 8;
    #pragma unroll
    for (int j = 0; j < 8; ++j) { int c = bt[j]; K += c; if (j < sblk) off += c; }
    int d4 = t & 31;
    int g = t >> 5;
    float4 wcol[16];
    #pragma unroll
    for (int k = 0; k < 16; ++k) wcol[k] = *(const float4*)&wfp[k * ED + d4 * 4];
    const float* img = x + ((size_t)b * IMH + row * 4) * IMW;
    #pragma unroll
    for (int k = 0; k < 2; ++k) {
        int idx = t + 256 * k;                  // float4 index 0..511
        int r = idx >> 7, c4 = idx & 127;
        *(float4*)&smx[r][c4 * 4] = *(const float4*)&img[r * IMW + c4 * 4];
    }
    __syncthreads();
    const int* posb = pos_rel + ((size_t)b << 14);
    float4 fill = *(const float4*)&temb[ED + d4 * 4];
    float4 bse = *(const float4*)&bfp[d4 * 4];
    float4 base = make_float4(bse.x + fill.x, bse.y + fill.y, bse.z + fill.z, bse.w + fill.w);
    float* tok = out + ((size_t)b * NTOK + NC) * ED;
    #pragma unroll
    for (int pp = 0; pp < 16; ++pp) {
        int p = g + pp * 8;
        int i = i0 + p;
        int pr = posb[i];
        if (pr >= 0) {
            int ps = pr + off;
            float4 acc = base;
            #pragma unroll
            for (int r = 0; r < 4; ++r) {
                float4 vv = *(const float4*)&smx[r][p * 4];
                acc.x += vv.x * wcol[4 * r].x + vv.y * wcol[4 * r + 1].x + vv.z * wcol[4 * r + 2].x + vv.w * wcol[4 * r + 3].x;
                acc.y += vv.x * wcol[4 * r].y + vv.y * wcol[4 * r + 1].y + vv.z * wcol[4 * r + 2].y + vv.w * wcol[4 * r + 3].y;
                acc.z += vv.x * wcol[4 * r].z + vv.y * wcol[4 * r + 1].z + vv.z * wcol[4 * r + 2].z + vv.w * wcol[4 * r + 3].z;
                acc.w += vv.x * wcol[4 * r].w + vv.y * wcol[4 * r + 1].w + vv.z * wcol[4 * r + 2].w + vv.w * wcol[4 * r + 3].w;
            }
            nt_store4v(tok + ((size_t)ps * 32 + d4) * 4, acc);
        }
        if (i >= K) {
            nt_store4v(tok + ((size_t)i * 32 + d4) * 4, fill);
        }
    }
}

// ---------------- cooperative fused kernel ---------------------------------
__global__ __launch_bounds__(256, 4) void fused_all(const float* __restrict__ x,
                                                    const float* __restrict__ wc,
                                                    const float* __restrict__ bc,
                                                    const float* __restrict__ wfp,
                                                    const float* __restrict__ bfp,
                                                    const float* __restrict__ temb,
                                                    float* __restrict__ out,
                                                    float* __restrict__ mask_out,
                                                    double* __restrict__ edges,
                                                    double* __restrict__ tsum,
                                                    int* __restrict__ pos_rel,
                                                    int* __restrict__ btot) {
    int blk = blockIdx.x;
    int t = threadIdx.x;
    cg::grid_group grid = cg::this_grid();
    if (blk < 512) edge_role(blk, t, x, edges, tsum);
    coarse_role(blk, t, x, wc, bc, temb, out);
    grid.sync();
    if (blk < 64) scan_role(blk, t, edges, tsum, pos_rel, btot, mask_out);
    grid.sync();
    fine_role(blk, t, x, wfp, bfp, temb, pos_rel, btot, out);
}

// ---------------- fallback split kernels (identical arithmetic) ------------
__global__ __launch_bounds__(256) void k_p1(const float* __restrict__ x,
                                            const float* __restrict__ wc,
                                            const float* __restrict__ bc,
                                            const float* __restrict__ temb,
                                            float* __restrict__ out,
                                            double* __restrict__ edges,
                                            double* __restrict__ tsum) {
    int blk = blockIdx.x, t = threadIdx.x;
    if (blk < 512) edge_role(blk, t, x, edges, tsum);
    coarse_role(blk, t, x, wc, bc, temb, out);
}
__global__ __launch_bounds__(256) void k_p2(const double* __restrict__ edges,
                                            const double* __restrict__ tsum,
                                            int* __restrict__ pos_rel,
                                            int* __restrict__ btot,
                                            float* __restrict__ mask_out) {
    scan_role(blockIdx.x, threadIdx.x, edges, tsum, pos_rel, btot, mask_out);
}
__global__ __launch_bounds__(256) void k_p3(const float* __restrict__ x,
                                            const float* __restrict__ wfp,
                                            const float* __restrict__ bfp,
                                            const float* __restrict__ temb,
                                            const int* __restrict__ pos_rel,
                                            const int* __restrict__ btot,
                                            float* __restrict__ out) {
    fine_role(blockIdx.x, threadIdx.x, x, wfp, bfp, temb, pos_rel, btot, out);
}

extern "C" void kernel_launch(void* const* d_in, const int* in_sizes, int n_in,
                              void* d_out, int out_size, void* d_ws, size_t ws_size,
                              hipStream_t stream) {
    const float* x    = (const float*)d_in[0];
    const float* wc   = (const float*)d_in[1];
    const float* bc   = (const float*)d_in[2];
    const float* wfp  = (const float*)d_in[3];
    const float* bfp  = (const float*)d_in[4];
    const float* temb = (const float*)d_in[5];
    float* out = (float*)d_out;

    char* wsb = (char*)d_ws;
    double* edges   = (double*)wsb;                                   // 1 MiB
    double* tsum    = (double*)(wsb + (size_t)BATCH * NF * 8);        // 4 KiB
    int*    pos_rel = (int*)(wsb + (size_t)BATCH * NF * 8 + 4096);    // 512 KiB
    int*    btot    = (int*)(wsb + (size_t)BATCH * NF * 8 + 4096 + (size_t)BATCH * NF * 4);
    float*  mask_out = out + (size_t)BATCH * NTOK * ED;

    void* args[] = {(void*)&x, (void*)&wc, (void*)&bc, (void*)&wfp, (void*)&bfp,
                    (void*)&temb, (void*)&out, (void*)&mask_out, (void*)&edges,
                    (void*)&tsum, (void*)&pos_rel, (void*)&btot};
    hipError_t err = hipLaunchCooperativeKernel((void*)fused_all, dim3(1024), dim3(256),
                                                args, 0, stream);
    if (err != hipSuccess) {
        // fallback: identical arithmetic as 3 serial kernels
        k_p1<<<dim3(1024), 256, 0, stream>>>(x, wc, bc, temb, out, edges, tsum);
        k_p2<<<dim3(64), 256, 0, stream>>>(edges, tsum, pos_rel, btot, mask_out);
        k_p3<<<dim3(1024), 256, 0, stream>>>(x, wfp, bfp, temb, pos_rel, btot, out);
    }
}

// Round 8
// 51.218 us; speedup vs baseline: 5.6212x; 5.6212x over previous
//
#include <hip/hip_runtime.h>

#define IMH 512
#define IMW 512
#define BATCH 8
#define NTOK 20480
#define NC 4096
#define NF 16384
#define ED 128

typedef float vf4 __attribute__((ext_vector_type(4)));

__device__ __forceinline__ void nt_store4(float* p, float a, float b, float c, float d) {
    vf4 v = {a, b, c, d};
    __builtin_nontemporal_store(v, (vf4*)p);
}
__device__ __forceinline__ void nt_store4v(float* p, float4 v) {
    nt_store4(p, v.x, v.y, v.z, v.w);
}

// ---------------- Kernel 1: coarse embed (blocks 0-1023) + edge map (1024-1535)
__global__ __launch_bounds__(256) void k1_edge_coarse(const float* __restrict__ x,
                                                      const float* __restrict__ wc,
                                                      const float* __restrict__ bc,
                                                      const float* __restrict__ temb,
                                                      float* __restrict__ out,
                                                      double* __restrict__ edges,
                                                      double* __restrict__ tsum) {
    __shared__ float esm[66][68];
    __shared__ double dred[4];
    int blk = blockIdx.x;
    int t = threadIdx.x;
    int lane = t & 63, wid = t >> 6;
    if (blk < 1024) {
        // ---- coarse role: 32 patches/block, wave-uniform scalar loads, no LDS
        int b = blk >> 7;
        int pblk = (blk & 127) * 32;
        int wv = __builtin_amdgcn_readfirstlane(t >> 6);  // wave id 0..3
        int h = wv & 1;
        int p0 = pblk + (wv >> 1) * 16;
        int d = h * 64 + lane;
        float wcol[64];
        #pragma unroll
        for (int k = 0; k < 64; ++k) wcol[k] = wc[k * ED + d];
        float base = bc[d] + temb[d];
        const float* img = x + ((size_t)b * IMH + (p0 >> 6) * 8) * IMW + (p0 & 63) * 8;
        float* dst = out + ((size_t)b * NTOK + p0) * ED + d;
        #pragma unroll
        for (int p = 0; p < 16; ++p) {
            const float* pimg = img + p * 8;    // wave-uniform -> scalar loads
            float acc = base;
            #pragma unroll
            for (int r = 0; r < 8; ++r) {
                const float* rp = pimg + r * IMW;
                acc += rp[0] * wcol[r * 8 + 0] + rp[1] * wcol[r * 8 + 1]
                     + rp[2] * wcol[r * 8 + 2] + rp[3] * wcol[r * 8 + 3]
                     + rp[4] * wcol[r * 8 + 4] + rp[5] * wcol[r * 8 + 5]
                     + rp[6] * wcol[r * 8 + 6] + rp[7] * wcol[r * 8 + 7];
            }
            __builtin_nontemporal_store(acc, dst + (size_t)p * ED);
        }
    } else {
        // ---- edge role: one 64x64 tile -> 16x16 fp64 cells + fp64 tile sum
        int blk2 = blk - 1024;
        int b = blk2 >> 6;
        int tile = blk2 & 63;
        int ty0 = (tile >> 3) * 64;
        int tx0 = (tile & 7) * 64;
        const float* img = x + (size_t)b * (IMH * IMW);
        for (int idx = t; idx < 66 * 66; idx += 256) {
            int r = idx / 66, c = idx - r * 66;
            int gy = ty0 - 1 + r, gx = tx0 - 1 + c;
            float v = 0.f;
            if (gy >= 0 && gy < IMH && gx >= 0 && gx < IMW) v = img[gy * IMW + gx];
            esm[r][c] = v;
        }
        __syncthreads();
        int cy = t >> 4, cx = t & 15;
        double acc = 0.0;
        #pragma unroll
        for (int dy = 0; dy < 4; ++dy) {
            int py = cy * 4 + dy + 1;
            #pragma unroll
            for (int dx = 0; dx < 4; ++dx) {
                int px = cx * 4 + dx + 1;
                double a00 = (double)esm[py - 1][px - 1];
                double a01 = (double)esm[py - 1][px];
                double a02 = (double)esm[py - 1][px + 1];
                double a10 = (double)esm[py][px - 1];
                double a12 = (double)esm[py][px + 1];
                double a20 = (double)esm[py + 1][px - 1];
                double a21 = (double)esm[py + 1][px];
                double a22 = (double)esm[py + 1][px + 1];
                double sx = (a02 + 2.0 * a12 + a22) - (a00 + 2.0 * a10 + a20);
                double sy = (a20 + 2.0 * a21 + a22) - (a00 + 2.0 * a01 + a02);
                acc += sqrt(sx * sx + sy * sy);
            }
        }
        double cell = acc * (1.0 / 16.0);
        int gy = (ty0 >> 2) + cy;
        int gx = (tx0 >> 2) + cx;
        edges[((size_t)b << 14) + gy * 128 + gx] = cell;
        double sc = cell;
        #pragma unroll
        for (int off = 32; off > 0; off >>= 1) sc += __shfl_xor(sc, off);
        if (lane == 0) dred[wid] = sc;
        __syncthreads();
        if (t == 0) tsum[b * 64 + tile] = dred[0] + dred[1] + dred[2] + dred[3];
    }
}

// ---------------- Kernel 2: fine embed, self-sufficient mask/prefix --------
// grid (128, 8): one patch-row (128 fine patches) per block, 256 threads.
// Each block recomputes its batch's full mask prefix from edges (L2-resident).
__global__ __launch_bounds__(256) void k2_fine(const float* __restrict__ x,
                                               const float* __restrict__ wfp,
                                               const float* __restrict__ bfp,
                                               const float* __restrict__ temb,
                                               const double* __restrict__ edges,
                                               const double* __restrict__ tsum,
                                               float* __restrict__ out,
                                               float* __restrict__ mask_out) {
    int b = blockIdx.y;
    int row = blockIdx.x;          // 0..127 (fine patch-row == mask cell-row)
    int t = threadIdx.x;
    int lane = t & 63, wid = t >> 6;
    __shared__ float smx[4][512];
    __shared__ int excl_s[256];
    __shared__ unsigned long long bits_s[256];
    __shared__ int wtot[4];

    // deterministic fixed-order fp64 mean (bit-identical to prior rounds)
    const double* ts = tsum + b * 64;
    double total = 0.0;
    #pragma unroll
    for (int j = 0; j < 64; ++j) total += ts[j];
    double mean = total * (1.0 / 16384.0);

    // this thread's 64 cells -> bitmask
    const double* e = edges + ((size_t)b << 14) + t * 64;
    unsigned long long mybits = 0ULL;
    #pragma unroll
    for (int j = 0; j < 32; ++j) {
        double2 dv = *(const double2*)&e[j * 2];
        if (dv.x > mean) mybits |= (1ULL << (2 * j));
        if (dv.y > mean) mybits |= (1ULL << (2 * j + 1));
    }
    int cnt = __popcll(mybits);
    int incl = cnt;
    #pragma unroll
    for (int off = 1; off < 64; off <<= 1) {
        int up = __shfl_up(incl, off);
        if (lane >= off) incl += up;
    }
    if (lane == 63) wtot[wid] = incl;
    bits_s[t] = mybits;
    __syncthreads();
    int woff = 0, K = 0;
    #pragma unroll
    for (int w = 0; w < 4; ++w) { int c = wtot[w]; K += c; if (w < wid) woff += c; }
    excl_s[t] = woff + incl - cnt;

    // stage this row's x pixels (4 rows x 512)
    const float* img = x + ((size_t)b * IMH + row * 4) * IMW;
    #pragma unroll
    for (int k = 0; k < 2; ++k) {
        int idx = t + 256 * k;
        int r = idx >> 7, c4 = idx & 127;
        *(float4*)&smx[r][c4 * 4] = *(const float4*)&img[r * IMW + c4 * 4];
    }
    __syncthreads();

    int base = excl_s[2 * row];                       // cells before i0
    unsigned long long lo = bits_s[2 * row];
    unsigned long long hi = bits_s[2 * row + 1];

    // mask output for this row (1:1 with fine patches)
    if (t < 128) {
        unsigned long long bb = (t < 64) ? lo : hi;
        float mv = ((bb >> (t & 63)) & 1ULL) ? 1.0f : 0.0f;
        __builtin_nontemporal_store(mv, mask_out + ((size_t)b << 14) + row * 128 + t);
    }

    int d4 = t & 31;
    int g = t >> 5;
    float4 wcol[16];
    #pragma unroll
    for (int k = 0; k < 16; ++k) wcol[k] = *(const float4*)&wfp[k * ED + d4 * 4];
    float4 fill = *(const float4*)&temb[ED + d4 * 4];
    float4 bse = *(const float4*)&bfp[d4 * 4];
    float4 fbase = make_float4(bse.x + fill.x, bse.y + fill.y, bse.z + fill.z, bse.w + fill.w);
    float* tok = out + ((size_t)b * NTOK + NC) * ED;
    int i0 = row * 128;
    #pragma unroll
    for (int pp = 0; pp < 16; ++pp) {
        int p = g + pp * 8;
        int i = i0 + p;
        unsigned long long bb = (p < 64) ? lo : hi;
        if ((bb >> (p & 63)) & 1ULL) {
            int below = (p < 64)
                ? __popcll(lo & ((1ULL << p) - 1))
                : __popcll(lo) + __popcll(hi & ((1ULL << (p - 64)) - 1));
            int ps = base + below;
            float4 acc = fbase;
            #pragma unroll
            for (int r = 0; r < 4; ++r) {
                float4 vv = *(const float4*)&smx[r][p * 4];
                acc.x += vv.x * wcol[4 * r].x + vv.y * wcol[4 * r + 1].x + vv.z * wcol[4 * r + 2].x + vv.w * wcol[4 * r + 3].x;
                acc.y += vv.x * wcol[4 * r].y + vv.y * wcol[4 * r + 1].y + vv.z * wcol[4 * r + 2].y + vv.w * wcol[4 * r + 3].y;
                acc.z += vv.x * wcol[4 * r].z + vv.y * wcol[4 * r + 1].z + vv.z * wcol[4 * r + 2].z + vv.w * wcol[4 * r + 3].z;
                acc.w += vv.x * wcol[4 * r].w + vv.y * wcol[4 * r + 1].w + vv.z * wcol[4 * r + 2].w + vv.w * wcol[4 * r + 3].w;
            }
            nt_store4v(tok + ((size_t)ps * 32 + d4) * 4, acc);
        }
        if (i >= K) {
            nt_store4v(tok + ((size_t)i * 32 + d4) * 4, fill);
        }
    }
}

extern "C" void kernel_launch(void* const* d_in, const int* in_sizes, int n_in,
                              void* d_out, int out_size, void* d_ws, size_t ws_size,
                              hipStream_t stream) {
    const float* x    = (const float*)d_in[0];
    const float* wc   = (const float*)d_in[1];
    const float* bc   = (const float*)d_in[2];
    const float* wfp  = (const float*)d_in[3];
    const float* bfp  = (const float*)d_in[4];
    const float* temb = (const float*)d_in[5];
    float* out = (float*)d_out;

    char* wsb = (char*)d_ws;
    double* edges = (double*)wsb;                              // 1 MiB
    double* tsum  = (double*)(wsb + (size_t)BATCH * NF * 8);   // 4 KiB
    float* mask_out = out + (size_t)BATCH * NTOK * ED;

    k1_edge_coarse<<<dim3(1536), 256, 0, stream>>>(x, wc, bc, temb, out, edges, tsum);
    k2_fine<<<dim3(128, BATCH), 256, 0, stream>>>(x, wfp, bfp, temb, edges, tsum, out, mask_out);
}